// Round 2
// baseline (362.025 us; speedup 1.0000x reference)
//
#include <hip/hip_runtime.h>
#include <cstddef>

typedef float f4 __attribute__((ext_vector_type(4)));

#define NROWS 16384
#define NCOLS 2048
#define NGRP  128
#define EPS_W 1e-5f
#define NS_T  5

// ---- stats geometry ----
#define TROWS 32
#define S_CH  128                 // row chunks (blockIdx.y)
#define S_RPB (NROWS / S_CH)      // 128 rows per block
#define S_NT  (S_RPB / TROWS)     // 4 tiles
#define PART_STRIDE 272           // 16 mean sums + 256 second moments per group

// ---- apply geometry ----
#define A_STRIPES 256
#define A_RPB (NROWS / A_STRIPES) // 64 rows per block

// ---------------- Phase 1: per-group mean + second-moment, atomic reduce ----------------
__global__ __launch_bounds__(256) void k_stats(const float* __restrict__ x,
                                               float* __restrict__ part) {
  __shared__ __align__(16) float tile[TROWS * 256];   // 32 KB, single buffer
  const int cb   = blockIdx.x;      // 0..7 column block (16 groups)
  const int ch   = blockIdx.y;      // 0..127 row chunk
  const int t    = threadIdx.x;
  const int col0 = cb << 8;
  const int r0   = ch * S_RPB;

  const int g  = t >> 4;            // group within block 0..15
  const int ti = t & 15;
  const int tc = (ti >> 2) << 2;    // row quad of cov tile
  const int td = (ti & 3) << 2;     // col quad of cov tile

  float mac = 0.f;                  // mean accumulator for column col0+t
  float acc[4][4] = {{0.f}};

  f4 st[8];
  // prologue: issue loads for tile 0
#pragma unroll
  for (int i = 0; i < 8; ++i) {
    const int f = (i << 8) | t;
    const int r = f >> 6, cq = f & 63;
    st[i] = *(const f4*)(x + (size_t)(r0 + r) * NCOLS + col0 + (cq << 2));
  }

  for (int tb = 0; tb < S_NT; ++tb) {
    __syncthreads();                // previous tile's compute done
#pragma unroll
    for (int i = 0; i < 8; ++i) {
      const int f = (i << 8) | t;
      *(f4*)(&tile[f << 2]) = st[i];
    }
    __syncthreads();                // tile visible
    if (tb + 1 < S_NT) {            // prefetch next tile into regs (overlaps compute)
      const int rn = r0 + (tb + 1) * TROWS;
#pragma unroll
      for (int i = 0; i < 8; ++i) {
        const int f = (i << 8) | t;
        const int r = f >> 6, cq = f & 63;
        st[i] = *(const f4*)(x + (size_t)(rn + r) * NCOLS + col0 + (cq << 2));
      }
    }
#pragma unroll 4
    for (int r = 0; r < TROWS; ++r) {
      const float* row = tile + r * 256;
      mac += row[t];
      const f4 xa = *(const f4*)(row + (g << 4) + tc);
      const f4 xb = *(const f4*)(row + (g << 4) + td);
#pragma unroll
      for (int i = 0; i < 4; ++i)
#pragma unroll
        for (int j = 0; j < 4; ++j)
          acc[i][j] += xa[i] * xb[j];
    }
  }

  float* pg = part + (size_t)((cb << 4) + g) * PART_STRIDE;
  atomicAdd(&pg[ti], mac);          // column sums: group g, channel ti
#pragma unroll
  for (int i = 0; i < 4; ++i)
#pragma unroll
    for (int j = 0; j < 4; ++j)
      atomicAdd(&pg[16 + (tc + i) * 16 + (td + j)], acc[i][j]);
}

// ---------------- Phase 2: Newton-Schulz + fold scalars into A2/b2 ----------------
__global__ __launch_bounds__(256) void k_ns(const float* __restrict__ part,
                                            const float* __restrict__ swm,
                                            const float* __restrict__ swv,
                                            const float* __restrict__ wgt,
                                            const float* __restrict__ bia,
                                            float* __restrict__ A2,
                                            float* __restrict__ b2) {
  __shared__ float sP[256], sA[256], sB[256], sN[256], smean[16];
  __shared__ float strace;
  const int G = blockIdx.x;
  const int t = threadIdx.x;
  const int c = t >> 4, d = t & 15;

  const float m2 = part[(size_t)G * PART_STRIDE + 16 + t];
  if (t < 16) smean[t] = part[(size_t)G * PART_STRIDE + t] * (1.f / NROWS);
  __syncthreads();

  const float a0 = swm[0], a1 = swm[1];
  const float am = fmaxf(a0, a1);
  const float e0 = expf(a0 - am), e1 = expf(a1 - am);
  const float mw0 = e0 / (e0 + e1), mw1 = e1 / (e0 + e1);
  const float v0 = swv[0], v1 = swv[1];
  const float vm = fmaxf(v0, v1);
  const float f0 = expf(v0 - vm), f1 = expf(v1 - vm);
  const float vw0 = f0 / (f0 + f1);

  float cov = m2 * (1.f / NROWS) - smean[c] * smean[d];
  cov = vw0 * cov + ((c == d) ? EPS_W : 0.f);
  sN[t] = cov;
  __syncthreads();
  if (t == 0) {
    float tr = 0.f;
#pragma unroll
    for (int k = 0; k < 16; ++k) tr += sN[k * 17];
    strace = 1.f / tr;
  }
  __syncthreads();
  const float rTr = strace;
  sN[t] = cov * rTr;               // covN
  sP[t] = (c == d) ? 1.f : 0.f;    // P = I
  __syncthreads();

  for (int it = 0; it < NS_T; ++it) {
    float p2 = 0.f;
#pragma unroll
    for (int k = 0; k < 16; ++k) p2 += sP[c * 16 + k] * sP[k * 16 + d];
    sA[t] = p2;
    __syncthreads();
    float p3 = 0.f;
#pragma unroll
    for (int k = 0; k < 16; ++k) p3 += sA[c * 16 + k] * sP[k * 16 + d];
    sB[t] = p3;
    __syncthreads();
    float qv = 0.f;
#pragma unroll
    for (int k = 0; k < 16; ++k) qv += sB[c * 16 + k] * sN[k * 16 + d];
    const float np = 1.5f * sP[t] - 0.5f * qv;
    __syncthreads();
    sP[t] = np;
    __syncthreads();
  }

  const float wmv = sP[t] * sqrtf(rTr);
  const float wr = wgt[(G << 4) + c];
  A2[(size_t)G * 256 + t] = wmv * (1.f - mw1) * wr;
  sA[t] = wmv * smean[d];
  __syncthreads();
  if (t < 16) {
    float s = 0.f;
#pragma unroll
    for (int k = 0; k < 16; ++k) s += sA[t * 16 + k];
    b2[(G << 4) + t] = -mw0 * s * wgt[(G << 4) + t] + bia[(G << 4) + t];
  }
}

// ---------------- Phase 3: y = A2 @ x + b2, LDS-free streaming ----------------
__device__ __forceinline__ float dot16(const f4* ar, f4 u0, f4 u1, f4 u2, f4 u3) {
  const f4 p = ar[0] * u0 + ar[1] * u1 + ar[2] * u2 + ar[3] * u3;
  return p.x + p.y + p.z + p.w;
}

__global__ __launch_bounds__(256) void k_apply(const float* __restrict__ x,
                                               const float* __restrict__ A2,
                                               const float* __restrict__ b2,
                                               float* __restrict__ y) {
  const int cb  = blockIdx.x;     // 0..7
  const int stb = blockIdx.y;     // 0..A_STRIPES-1
  const int t   = threadIdx.x;
  const int q   = t & 3;          // output quad 0..3
  const int g   = (t >> 2) & 15;  // group within column block
  const int ph  = t >> 6;         // wave id = row phase 0..3
  const int G   = (cb << 4) | g;
  const int col0 = cb << 8;

  f4 a[4][4];
#pragma unroll
  for (int i = 0; i < 4; ++i)
#pragma unroll
    for (int dq = 0; dq < 4; ++dq)
      a[i][dq] = *(const f4*)(A2 + (size_t)G * 256 + ((q << 2) + i) * 16 + (dq << 2));
  const f4 bv = *(const f4*)(b2 + (G << 4) + (q << 2));

  const int r0 = stb * A_RPB + ph;
  const size_t xoff = (size_t)col0 + (g << 4);
  const size_t yoff = (size_t)col0 + ((size_t)(t & 63) << 2);  // contiguous 1KB/wave

  for (int i = 0; i < A_RPB / 4; i += 2) {
    const size_t ra = (size_t)(r0 + 4 * i) * NCOLS;
    const size_t rb = (size_t)(r0 + 4 * i + 4) * NCOLS;
    const float* pa = x + ra + xoff;
    const float* pb = x + rb + xoff;
    // issue all 8 loads up front for MLP
    const f4 u0 = __builtin_nontemporal_load((const f4*)(pa + 0));
    const f4 u1 = __builtin_nontemporal_load((const f4*)(pa + 4));
    const f4 u2 = __builtin_nontemporal_load((const f4*)(pa + 8));
    const f4 u3 = __builtin_nontemporal_load((const f4*)(pa + 12));
    const f4 v0 = __builtin_nontemporal_load((const f4*)(pb + 0));
    const f4 v1 = __builtin_nontemporal_load((const f4*)(pb + 4));
    const f4 v2 = __builtin_nontemporal_load((const f4*)(pb + 8));
    const f4 v3 = __builtin_nontemporal_load((const f4*)(pb + 12));

    f4 oa, ob;
    oa.x = bv.x + dot16(a[0], u0, u1, u2, u3);
    oa.y = bv.y + dot16(a[1], u0, u1, u2, u3);
    oa.z = bv.z + dot16(a[2], u0, u1, u2, u3);
    oa.w = bv.w + dot16(a[3], u0, u1, u2, u3);
    __builtin_nontemporal_store(oa, (f4*)(y + ra + yoff));
    ob.x = bv.x + dot16(a[0], v0, v1, v2, v3);
    ob.y = bv.y + dot16(a[1], v0, v1, v2, v3);
    ob.z = bv.z + dot16(a[2], v0, v1, v2, v3);
    ob.w = bv.w + dot16(a[3], v0, v1, v2, v3);
    __builtin_nontemporal_store(ob, (f4*)(y + rb + yoff));
  }
}

extern "C" void kernel_launch(void* const* d_in, const int* in_sizes, int n_in,
                              void* d_out, int out_size, void* d_ws, size_t ws_size,
                              hipStream_t stream) {
  (void)in_sizes; (void)n_in; (void)out_size; (void)ws_size;
  const float* x   = (const float*)d_in[0];
  const float* swm = (const float*)d_in[1];
  const float* swv = (const float*)d_in[2];
  const float* wgt = (const float*)d_in[3];
  const float* bia = (const float*)d_in[4];
  float* out = (float*)d_out;

  float* part = (float*)d_ws;                          // 128*272 floats = 139 KB
  float* A2   = part + (size_t)NGRP * PART_STRIDE;
  float* b2   = A2 + (size_t)NGRP * 256;

  hipMemsetAsync(part, 0, (size_t)NGRP * PART_STRIDE * sizeof(float), stream);
  k_stats<<<dim3(8, S_CH), 256, 0, stream>>>(x, part);
  k_ns<<<NGRP, 256, 0, stream>>>(part, swm, swv, wgt, bia, A2, b2);
  k_apply<<<dim3(8, A_STRIPES), 256, 0, stream>>>(x, A2, b2, out);
}

// Round 3
// 305.390 us; speedup vs baseline: 1.1855x; 1.1855x over previous
//
#include <hip/hip_runtime.h>
#include <cstddef>

typedef float f4 __attribute__((ext_vector_type(4)));

#define NROWS 16384
#define NCOLS 2048
#define NGRP  128
#define EPS_W 1e-5f
#define NS_T  5
#define PART_STRIDE 272

// ---- stats geometry: grid (8, S_CH), 512 threads (8 waves, 2 halves x 4 tc-waves)
#define S_CH 32
#define S_RPB (NROWS / S_CH)       // 512 rows per block
#define S_HROWS (S_RPB / 2)        // 256 rows per half
#define S_STEPS (S_HROWS / 4)      // 64 steps (4 rows per step via p-lanes)

// ---- apply geometry ----
#define A_STRIPES 256
#define A_RPB (NROWS / A_STRIPES)  // 64 rows per block

__device__ __forceinline__ f4 sxor(f4 v, int m) {
  f4 r;
  r.x = __shfl_xor(v.x, m, 64);
  r.y = __shfl_xor(v.y, m, 64);
  r.z = __shfl_xor(v.z, m, 64);
  r.w = __shfl_xor(v.w, m, 64);
  return r;
}

// ---------------- Phase 1: per-group mean + second-moment partials (no LDS tiles, no atomics)
__global__ __launch_bounds__(512) void k_stats(const float* __restrict__ x,
                                               float* __restrict__ part) {
  __shared__ float red[64 * 72];    // 18.4 KB: half-1 partials, stride 72 (bank-spread)
  const int t  = threadIdx.x;
  const int cb = blockIdx.x;        // 0..7 column block (16 groups)
  const int ch = blockIdx.y;        // 0..31 row chunk
  const int g  = t & 15;            // group within column block
  const int p  = (t >> 4) & 3;      // row phase within wave
  const int tc = (t >> 6) & 3;      // cov row-quad owned by this wave
  const int h  = t >> 8;            // half (rows split)
  const int col0 = cb << 8;

  const size_t rbase = (size_t)ch * S_RPB + (size_t)h * S_HROWS + p;
  const float* bp = x + rbase * NCOLS + col0 + (g << 4);
  const size_t stp = (size_t)4 * NCOLS;

  const f4 zero = {0.f, 0.f, 0.f, 0.f};
  f4 acc[4][4];
#pragma unroll
  for (int i = 0; i < 4; ++i)
#pragma unroll
    for (int j = 0; j < 4; ++j) acc[i][j] = zero;
  f4 macc = zero;

  // 2-deep software pipeline: 5 loads per step (4 quads + xa select via L1-hit load)
  f4 q0, q1, q2, q3, xa, n0, n1, n2, n3, nx;
  q0 = *(const f4*)(bp + 0);
  q1 = *(const f4*)(bp + 4);
  q2 = *(const f4*)(bp + 8);
  q3 = *(const f4*)(bp + 12);
  xa = *(const f4*)(bp + (tc << 2));

  for (int s = 0; s < S_STEPS; ++s) {
    if (s + 1 < S_STEPS) {
      const float* pn = bp + (size_t)(s + 1) * stp;
      n0 = *(const f4*)(pn + 0);
      n1 = *(const f4*)(pn + 4);
      n2 = *(const f4*)(pn + 8);
      n3 = *(const f4*)(pn + 12);
      nx = *(const f4*)(pn + (tc << 2));
    }
    macc += xa;
#pragma unroll
    for (int i = 0; i < 4; ++i) {
      const float sc = xa[i];
      acc[i][0] += sc * q0;
      acc[i][1] += sc * q1;
      acc[i][2] += sc * q2;
      acc[i][3] += sc * q3;
    }
    q0 = n0; q1 = n1; q2 = n2; q3 = n3; xa = nx;
    if ((s & 7) == 7) __syncthreads();   // keep the 8 waves' streams L1/L2-coherent
  }

  // reduce across the 4 p-lanes (bits 4,5 of lane id)
#pragma unroll
  for (int i = 0; i < 4; ++i)
#pragma unroll
    for (int j = 0; j < 4; ++j) {
      acc[i][j] += sxor(acc[i][j], 16);
      acc[i][j] += sxor(acc[i][j], 32);
    }
  macc += sxor(macc, 16);
  macc += sxor(macc, 32);

  // combine the two halves via LDS, then one deterministic global partial write
  const int slot = ((tc << 4) | g) * 72;
  if (h == 1 && p == 0) {
    *(f4*)&red[slot] = macc;
#pragma unroll
    for (int i = 0; i < 4; ++i)
#pragma unroll
      for (int j = 0; j < 4; ++j)
        *(f4*)&red[slot + 4 + i * 16 + (j << 2)] = acc[i][j];
  }
  __syncthreads();
  if (h == 0 && p == 0) {
    macc += *(const f4*)&red[slot];
#pragma unroll
    for (int i = 0; i < 4; ++i)
#pragma unroll
      for (int j = 0; j < 4; ++j)
        acc[i][j] += *(const f4*)&red[slot + 4 + i * 16 + (j << 2)];

    float* pg = part + ((size_t)ch * NGRP + (cb << 4) + g) * PART_STRIDE;
    *(f4*)(pg + (tc << 2)) = macc;                       // mean sums, channels tc*4..+3
#pragma unroll
    for (int i = 0; i < 4; ++i)
#pragma unroll
      for (int j = 0; j < 4; ++j)
        *(f4*)(pg + 16 + (tc << 6) + i * 16 + (j << 2)) = acc[i][j];
  }
}

// ---------------- Phase 2: reduce chunks, Newton-Schulz, fold scalars into A2/b2
__global__ __launch_bounds__(256) void k_ns(const float* __restrict__ part,
                                            const float* __restrict__ swm,
                                            const float* __restrict__ swv,
                                            const float* __restrict__ wgt,
                                            const float* __restrict__ bia,
                                            float* __restrict__ A2,
                                            float* __restrict__ b2) {
  __shared__ float sred[272];
  __shared__ float sP[256], sA[256], sB[256], sN[256], smean[16];
  __shared__ float strace;
  const int G = blockIdx.x;
  const int t = threadIdx.x;
  const int c = t >> 4, d = t & 15;

  {
    float s0 = 0.f;
#pragma unroll 4
    for (int ch = 0; ch < S_CH; ++ch)
      s0 += part[((size_t)ch * NGRP + G) * PART_STRIDE + t];
    sred[t] = s0;
    if (t < 16) {
      float s1 = 0.f;
#pragma unroll 4
      for (int ch = 0; ch < S_CH; ++ch)
        s1 += part[((size_t)ch * NGRP + G) * PART_STRIDE + 256 + t];
      sred[256 + t] = s1;
    }
  }
  __syncthreads();

  const float m2 = sred[16 + t];
  if (t < 16) smean[t] = sred[t] * (1.f / NROWS);
  __syncthreads();

  const float a0 = swm[0], a1 = swm[1];
  const float am = fmaxf(a0, a1);
  const float e0 = expf(a0 - am), e1 = expf(a1 - am);
  const float mw0 = e0 / (e0 + e1), mw1 = e1 / (e0 + e1);
  const float v0 = swv[0], v1 = swv[1];
  const float vm = fmaxf(v0, v1);
  const float f0 = expf(v0 - vm), f1 = expf(v1 - vm);
  const float vw0 = f0 / (f0 + f1);

  float cov = m2 * (1.f / NROWS) - smean[c] * smean[d];
  cov = vw0 * cov + ((c == d) ? EPS_W : 0.f);
  sN[t] = cov;
  __syncthreads();
  if (t == 0) {
    float tr = 0.f;
#pragma unroll
    for (int k = 0; k < 16; ++k) tr += sN[k * 17];
    strace = 1.f / tr;
  }
  __syncthreads();
  const float rTr = strace;
  sN[t] = cov * rTr;               // covN
  sP[t] = (c == d) ? 1.f : 0.f;    // P = I
  __syncthreads();

  for (int it = 0; it < NS_T; ++it) {
    float p2 = 0.f;
#pragma unroll
    for (int k = 0; k < 16; ++k) p2 += sP[c * 16 + k] * sP[k * 16 + d];
    sA[t] = p2;
    __syncthreads();
    float p3 = 0.f;
#pragma unroll
    for (int k = 0; k < 16; ++k) p3 += sA[c * 16 + k] * sP[k * 16 + d];
    sB[t] = p3;
    __syncthreads();
    float qv = 0.f;
#pragma unroll
    for (int k = 0; k < 16; ++k) qv += sB[c * 16 + k] * sN[k * 16 + d];
    const float np = 1.5f * sP[t] - 0.5f * qv;
    __syncthreads();
    sP[t] = np;
    __syncthreads();
  }

  const float wmv = sP[t] * sqrtf(rTr);
  const float wr = wgt[(G << 4) + c];
  A2[(size_t)G * 256 + t] = wmv * (1.f - mw1) * wr;
  sA[t] = wmv * smean[d];
  __syncthreads();
  if (t < 16) {
    float s = 0.f;
#pragma unroll
    for (int k = 0; k < 16; ++k) s += sA[t * 16 + k];
    b2[(G << 4) + t] = -mw0 * s * wgt[(G << 4) + t] + bia[(G << 4) + t];
  }
}

// ---------------- Phase 3: y = A2 @ x + b2, LDS-free, 2-stage pipelined
__device__ __forceinline__ float dot16(const f4* ar, f4 u0, f4 u1, f4 u2, f4 u3) {
  const f4 p = ar[0] * u0 + ar[1] * u1 + ar[2] * u2 + ar[3] * u3;
  return p.x + p.y + p.z + p.w;
}

#define LDP(P, A0, A1, A2_, A3)                                   \
  A0 = __builtin_nontemporal_load((const f4*)((P) + 0));          \
  A1 = __builtin_nontemporal_load((const f4*)((P) + 4));          \
  A2_ = __builtin_nontemporal_load((const f4*)((P) + 8));         \
  A3 = __builtin_nontemporal_load((const f4*)((P) + 12));

__global__ __launch_bounds__(256) void k_apply(const float* __restrict__ x,
                                               const float* __restrict__ A2,
                                               const float* __restrict__ b2,
                                               float* __restrict__ y) {
  const int cb  = blockIdx.x;     // 0..7
  const int stb = blockIdx.y;     // 0..A_STRIPES-1
  const int t   = threadIdx.x;
  const int q   = t & 3;          // output quad
  const int g   = (t >> 2) & 15;  // group within column block
  const int ph  = t >> 6;         // wave id = row phase
  const int G   = (cb << 4) | g;
  const int col0 = cb << 8;

  f4 a[4][4];
#pragma unroll
  for (int i = 0; i < 4; ++i)
#pragma unroll
    for (int dq = 0; dq < 4; ++dq)
      a[i][dq] = *(const f4*)(A2 + (size_t)G * 256 + ((q << 2) + i) * 16 + (dq << 2));
  const f4 bv = *(const f4*)(b2 + (G << 4) + (q << 2));

  const int r0 = stb * A_RPB + ph;
  const size_t xoff = (size_t)col0 + (g << 4);
  const size_t yoff = (size_t)col0 + ((size_t)(t & 63) << 2);

  const float* pa = x + (size_t)r0 * NCOLS + xoff;

  f4 u0, u1, u2, u3, v0, v1, v2, v3;
  f4 m0, m1, m2, m3, w0, w1, w2, w3;
  LDP(pa, u0, u1, u2, u3)
  LDP(pa + (size_t)4 * NCOLS, v0, v1, v2, v3)

  for (int s = 0; s < A_RPB / 8; ++s) {
    if (s + 1 < A_RPB / 8) {
      const float* pn = pa + (size_t)(s + 1) * 8 * NCOLS;
      LDP(pn, m0, m1, m2, m3)
      LDP(pn + (size_t)4 * NCOLS, w0, w1, w2, w3)
    }
    const size_t ra = (size_t)(r0 + 8 * s) * NCOLS;
    f4 oa, ob;
    oa.x = bv.x + dot16(a[0], u0, u1, u2, u3);
    oa.y = bv.y + dot16(a[1], u0, u1, u2, u3);
    oa.z = bv.z + dot16(a[2], u0, u1, u2, u3);
    oa.w = bv.w + dot16(a[3], u0, u1, u2, u3);
    __builtin_nontemporal_store(oa, (f4*)(y + ra + yoff));
    ob.x = bv.x + dot16(a[0], v0, v1, v2, v3);
    ob.y = bv.y + dot16(a[1], v0, v1, v2, v3);
    ob.z = bv.z + dot16(a[2], v0, v1, v2, v3);
    ob.w = bv.w + dot16(a[3], v0, v1, v2, v3);
    __builtin_nontemporal_store(ob, (f4*)(y + ra + (size_t)4 * NCOLS + yoff));
    u0 = m0; u1 = m1; u2 = m2; u3 = m3;
    v0 = w0; v1 = w1; v2 = w2; v3 = w3;
  }
}

extern "C" void kernel_launch(void* const* d_in, const int* in_sizes, int n_in,
                              void* d_out, int out_size, void* d_ws, size_t ws_size,
                              hipStream_t stream) {
  (void)in_sizes; (void)n_in; (void)out_size; (void)ws_size;
  const float* x   = (const float*)d_in[0];
  const float* swm = (const float*)d_in[1];
  const float* swv = (const float*)d_in[2];
  const float* wgt = (const float*)d_in[3];
  const float* bia = (const float*)d_in[4];
  float* out = (float*)d_out;

  float* part = (float*)d_ws;                          // 32*128*272*4 = 4.45 MB
  float* A2   = part + (size_t)S_CH * NGRP * PART_STRIDE;
  float* b2   = A2 + (size_t)NGRP * 256;

  k_stats<<<dim3(8, S_CH), 512, 0, stream>>>(x, part);
  k_ns<<<NGRP, 256, 0, stream>>>(part, swm, swv, wgt, bia, A2, b2);
  k_apply<<<dim3(8, A_STRIPES), 256, 0, stream>>>(x, A2, b2, out);
}